// Round 12
// baseline (181.875 us; speedup 1.0000x reference)
//
#include <hip/hip_runtime.h>

#define NN 50000
#define NE 800000
#define D 96
#define NL 3
#define NC 10
#define BN_EPS 1e-5f
#define INV_N (1.0f / (float)NN)
#define NB 196          // buckets of 256 dst nodes (dst >> 8)
#define CAP 6144        // max edges per bucket (mean 4082, +32 sigma)
#define EPB 2048        // edges per bin block
#define NREP 16         // stats replication factor (atomic contention)
#define WPAD 200        // padded wt row stride (shorts); 400B keeps 16B alignment
#define CASTB ((NN * D / 4 + 255) / 256)       // 4688
#define PREPWB ((NL * D * 192 + 255) / 256)    // 216

typedef _Float16 f16x8 __attribute__((ext_vector_type(8)));
typedef _Float16 h2t __attribute__((ext_vector_type(2)));
typedef unsigned short u16x8 __attribute__((ext_vector_type(8)));
typedef unsigned int u32x3 __attribute__((ext_vector_type(3)));
typedef float f32x4 __attribute__((ext_vector_type(4)));

// ----------------------------- fp16 helpers ---------------------------------
__device__ __forceinline__ unsigned short f2h(float x) {
    _Float16 h = (_Float16)x;
    return __builtin_bit_cast(unsigned short, h);
}
__device__ __forceinline__ unsigned int pkh2(float lo, float hi) {
    auto r = __builtin_amdgcn_cvt_pkrtz(lo, hi);   // __fp16 ext_vector(2)
    return __builtin_bit_cast(unsigned int, r);
}
__device__ __forceinline__ unsigned int pkadd(unsigned int a, unsigned int b) {
    h2t x = __builtin_bit_cast(h2t, a);
    h2t y = __builtin_bit_cast(h2t, b);
    h2t z = x + y;
    return __builtin_bit_cast(unsigned int, z);
}

// ---------------- edge index access (int32 vs int64 auto-detect) -------------
__device__ __forceinline__ int edge_at(const void* idx, int is64, long long pos) {
    if (is64) return (int)((const long long*)idx)[pos];
    return ((const int*)idx)[pos];
}

// fold NREP stat replicas -> LDS scale/shift (called by every block; L2-hot)
__device__ __forceinline__ void bn_fold(const float* __restrict__ stats,
                                        const float* __restrict__ gamma,
                                        const float* __restrict__ beta,
                                        float* sC, int t) {
    if (t < D) {
        float s = 0.f, q = 0.f;
        #pragma unroll
        for (int r = 0; r < NREP; ++r) {
            s += stats[r * 2 * D + t];
            q += stats[r * 2 * D + D + t];
        }
        float mu = s * INV_N;
        float va = q * INV_N - mu * mu;
        float sc = rsqrtf(va + BN_EPS) * gamma[t];
        sC[t] = sc;
        sC[D + t] = beta[t] - mu * sc;
    }
}

// merged front-end: cast x->fp16 | build padded W_T fp16 | detect + zero
__global__ void __launch_bounds__(256) prep_kernel(
        const float* __restrict__ x, unsigned short* __restrict__ xb,
        const float* __restrict__ wn, const float* __restrict__ ws,
        unsigned short* __restrict__ wt,
        const int* __restrict__ words, int* __restrict__ flag,
        int* __restrict__ cnt, float* __restrict__ stats) {
    int b = blockIdx.x;
    int t = threadIdx.x;
    if (b < CASTB) {
        int i = b * 256 + t;
        if (i < NN * D / 4) {
            float4 v = ((const float4*)x)[i];
            ushort4 o;
            o.x = f2h(v.x); o.y = f2h(v.y); o.z = f2h(v.z); o.w = f2h(v.w);
            ((ushort4*)xb)[i] = o;
        }
        return;
    }
    if (b < CASTB + PREPWB) {
        int i = (b - CASTB) * 256 + t;
        if (i < NL * D * 192) {
            int k = i % 192;
            int col = (i / 192) % D;
            int l = i / (192 * D);
            float v = (k < D) ? wn[(size_t)l * D * D + k * D + col]
                              : ws[(size_t)l * D * D + (k - D) * D + col];
            wt[((size_t)l * D + col) * WPAD + k] = f2h(v);
        }
        return;
    }
    // last block: detect + zeros
    __shared__ int any_nz;
    if (t == 0) any_nz = 0;
    __syncthreads();
    if (words[2 * t + 1] != 0) atomicOr(&any_nz, 1);
    __syncthreads();
    if (t == 0) *flag = any_nz ? 0 : 1;   // 1 => int64
    if (t < NB) cnt[t] = 0;
    for (int i = t; i < NL * NREP * 2 * D; i += 256) stats[i] = 0.f;
}

// bucket edges by dst>>8; write (src<<8)|(dst&255) into per-bucket regions
__global__ void __launch_bounds__(256) bin_kernel(
        const void* __restrict__ idx, const int* __restrict__ flag,
        int* __restrict__ cnt, unsigned int* __restrict__ binned, int E) {
    __shared__ int hist[256];
    __shared__ int gbase[256];
    __shared__ unsigned int pk[EPB];
    __shared__ unsigned char bkt[EPB];
    int t = threadIdx.x;
    int base = blockIdx.x * EPB;
    int is64 = *flag;
    hist[t] = 0;
    __syncthreads();
    #pragma unroll
    for (int j = 0; j < EPB / 256; ++j) {
        int i = t + j * 256;
        int e = base + i;
        if (e < E) {
            int s = edge_at(idx, is64, e);
            int d = edge_at(idx, is64, (long long)E + e);
            int b = d >> 8;
            bkt[i] = (unsigned char)b;
            pk[i] = ((unsigned int)s << 8) | (unsigned int)(d & 255);
            atomicAdd(&hist[b], 1);
        } else {
            bkt[i] = 0xFF;
        }
    }
    __syncthreads();
    int h = hist[t];
    int gb = 0;
    if (t < NB && h > 0) gb = atomicAdd(&cnt[t], h);
    gbase[t] = gb;
    hist[t] = 0;
    __syncthreads();
    #pragma unroll
    for (int j = 0; j < EPB / 256; ++j) {
        int i = t + j * 256;
        int b = bkt[i];
        if (b != 0xFF) {
            int loc = atomicAdd(&hist[b], 1);
            int pos = gbase[b] + loc;
            if (pos < CAP) binned[(size_t)b * CAP + pos] = pk[i];
        }
    }
}

// per bucket (1024 threads): bucket base via masked reduce; LDS degree count
// -> scan -> row_ptr/inv_deg; LDS-local CSR scatter; coalesced copy-out
__global__ void __launch_bounds__(1024) fill_bucket_kernel(
        const unsigned int* __restrict__ binned, const int* __restrict__ cnt,
        int* __restrict__ row_ptr, float* __restrict__ inv_deg,
        int* __restrict__ csr_src) {
    __shared__ int wsum[16];
    __shared__ int sbase;
    __shared__ int deg_l[256];
    __shared__ int lds_csr[CAP];
    int b = blockIdx.x;
    int t = threadIdx.x;
    int lane = t & 63, w = t >> 6;

    // base = sum cnt[i] for i < b (masked block reduce)
    {
        int v = (t < b) ? cnt[t] : 0;    // b < NB <= 256
        #pragma unroll
        for (int off = 32; off; off >>= 1) v += __shfl_xor(v, off);
        if (lane == 0) wsum[w] = v;
        __syncthreads();
        if (t == 0) {
            int r = 0;
            #pragma unroll
            for (int i = 0; i < 16; ++i) r += wsum[i];
            sbase = r;
        }
        __syncthreads();
    }
    int base = sbase;
    int count = cnt[b]; if (count > CAP) count = CAP;
    int n0 = b << 8;

    if (t < 256) deg_l[t] = 0;
    __syncthreads();
    const unsigned int* reg = binned + (size_t)b * CAP;
    for (int i = t; i < count; i += 1024) atomicAdd(&deg_l[reg[i] & 255], 1);
    __syncthreads();

    // exclusive scan of 256 degree values across 1024 threads (t>=256 -> 0)
    int v = (t < 256) ? deg_l[t] : 0;
    int x = v;
    #pragma unroll
    for (int off = 1; off < 64; off <<= 1) {
        int y = __shfl_up(x, off);
        if (lane >= off) x += y;
    }
    if (lane == 63) wsum[w] = x;
    __syncthreads();
    if (t == 0) {
        int r = 0;
        #pragma unroll
        for (int i = 0; i < 16; ++i) { int tt = wsum[i]; wsum[i] = r; r += tt; }
    }
    __syncthreads();
    int excl = x - v + wsum[w];
    int node = n0 + t;
    if (t < 256 && node < NN) {
        row_ptr[node] = base + excl;
        inv_deg[node] = 1.0f / (float)(v > 0 ? v : 1);
    }
    if (b == 0 && t == 0) row_ptr[NN] = NE;
    if (t < 256) deg_l[t] = excl;   // reuse as fill cursor
    __syncthreads();
    for (int i = t; i < count; i += 1024) {
        unsigned int pkv = reg[i];
        int loc = atomicAdd(&deg_l[pkv & 255], 1);
        lds_csr[loc] = (int)(pkv >> 8);
    }
    __syncthreads();
    for (int i = t; i < count; i += 1024) csr_src[base + i] = lds_csr[i];
}

// materialize post-BN+ReLU fp16 h; BN coefs folded in-block from replicas
__global__ void __launch_bounds__(256) bn_apply_kernel(
        const unsigned short* __restrict__ hpre,
        const float* __restrict__ stats,
        const float* __restrict__ gamma,
        const float* __restrict__ beta,
        unsigned short* __restrict__ hpost) {
    __shared__ float sC[2 * D];
    int t = threadIdx.x;
    bn_fold(stats, gamma, beta, sC, t);
    __syncthreads();
    int i = blockIdx.x * 256 + t;
    if (i >= NN * D / 8) return;
    uint4 v = ((const uint4*)hpre)[i];
    int f0 = (i * 8) % D;
    unsigned int* pv = (unsigned int*)&v;
    uint4 o;
    unsigned int* po = (unsigned int*)&o;
    #pragma unroll
    for (int j = 0; j < 4; ++j) {
        int f = f0 + 2 * j;
        h2t a = __builtin_bit_cast(h2t, pv[j]);
        float x0 = fmaxf(fmaf((float)a.x, sC[f], sC[D + f]), 0.f);
        float x1 = fmaxf(fmaf((float)a.y, sC[f + 1], sC[D + f + 1]), 0.f);
        po[j] = pkh2(x0, x1);
    }
    ((uint4*)hpost)[i] = o;
}

// one wave per dst node: 4 groups x 16 lanes; each group keeps 4 edges in
// flight (16 loads/wave outstanding). Lane owns 12 bytes (6 fp16).
__global__ void agg_kernel(const unsigned short* __restrict__ hb,
                           const int* __restrict__ row_ptr,
                           const int* __restrict__ csr_src,
                           const float* __restrict__ inv_deg,
                           unsigned short* __restrict__ aggb, int n) {
    int gid = blockIdx.x * blockDim.x + threadIdx.x;
    int node = gid >> 6;
    int lane = gid & 63;
    if (node >= n) return;
    int g = lane >> 4;          // edge-slot group 0..3
    unsigned int p12 = (lane & 15) * 12u;
    int beg = row_ptr[node], end = row_ptr[node + 1];
    const char* hbase = (const char*)hb;

    u32x3 a0 = {0,0,0}, a1 = {0,0,0}, a2 = {0,0,0}, a3 = {0,0,0};
    int i0 = (beg + g      < end) ? csr_src[beg + g]      : -1;
    int i1 = (beg + 4 + g  < end) ? csr_src[beg + 4 + g]  : -1;
    int i2 = (beg + 8 + g  < end) ? csr_src[beg + 8 + g]  : -1;
    int i3 = (beg + 12 + g < end) ? csr_src[beg + 12 + g] : -1;
    int e = beg;
    while (e < end) {
        u32x3 u0 = {0,0,0}, u1 = {0,0,0}, u2 = {0,0,0}, u3 = {0,0,0};
        if (i0 >= 0) u0 = *(const u32x3*)(hbase + (unsigned)i0 * 192u + p12);
        if (i1 >= 0) u1 = *(const u32x3*)(hbase + (unsigned)i1 * 192u + p12);
        if (i2 >= 0) u2 = *(const u32x3*)(hbase + (unsigned)i2 * 192u + p12);
        if (i3 >= 0) u3 = *(const u32x3*)(hbase + (unsigned)i3 * 192u + p12);
        int en = e + 16;
        i0 = (en + g      < end) ? csr_src[en + g]      : -1;
        i1 = (en + 4 + g  < end) ? csr_src[en + 4 + g]  : -1;
        i2 = (en + 8 + g  < end) ? csr_src[en + 8 + g]  : -1;
        i3 = (en + 12 + g < end) ? csr_src[en + 12 + g] : -1;
        #pragma unroll
        for (int r = 0; r < 3; ++r) {
            a0[r] = pkadd(a0[r], u0[r]);
            a1[r] = pkadd(a1[r], u1[r]);
            a2[r] = pkadd(a2[r], u2[r]);
            a3[r] = pkadd(a3[r], u3[r]);
        }
        e = en;
    }
    // combine 4 chains + cross-group reduce (lanes L, L+16, L+32, L+48)
    unsigned int acc[3];
    #pragma unroll
    for (int r = 0; r < 3; ++r) {
        unsigned int a = pkadd(pkadd(a0[r], a1[r]), pkadd(a2[r], a3[r]));
        a = pkadd(a, (unsigned int)__shfl_xor((int)a, 16));
        a = pkadd(a, (unsigned int)__shfl_xor((int)a, 32));
        acc[r] = a;
    }
    if (lane < 16) {
        float idg = inv_deg[node];
        u32x3 o;
        #pragma unroll
        for (int r = 0; r < 3; ++r) {
            h2t av = __builtin_bit_cast(h2t, acc[r]);
            o[r] = pkh2((float)av.x * idg, (float)av.y * idg);
        }
        *(u32x3*)((char*)aggb + (unsigned)node * 192u + p12) = o;
    }
}

// MFMA fp16 GEMM + fused BN stats. 4 row-tiles (256 nodes) per block:
// wt staged once, each B fragment ds_read feeds 4 MFMAs.
__global__ void __launch_bounds__(256) mfma_gemm_kernel(
        const unsigned short* __restrict__ aggb,
        const unsigned short* __restrict__ hb,     // post-BN (or xb for l=0)
        const unsigned short* __restrict__ wt,     // [96][WPAD] padded fp16
        const float* __restrict__ bias,
        unsigned short* __restrict__ hout,         // pre-BN fp16
        float* __restrict__ stats,                 // NREP replicas
        int n) {
    __shared__ float red[4][192];
    __shared__ unsigned short sW[D][WPAD];   // 38.4 KB
    int tid = threadIdx.x;
    int wave = tid >> 6;
    int lane = tid & 63;
    int m16 = lane & 15;
    int hi = lane >> 4;
    int rbase = blockIdx.x * 256 + wave * 16;   // tile t4 adds t4*64

    // 1) A-fragment global loads for all 4 tiles (48 independent b128s)
    f16x8 A[4][6];
    #pragma unroll
    for (int t4 = 0; t4 < 4; ++t4) {
        int ar = rbase + t4 * 64 + m16;
        int arc = ar < n ? ar : n - 1;
        const unsigned short* ap = aggb + (size_t)arc * D + hi * 8;
        const unsigned short* hp = hb + (size_t)arc * D + hi * 8;
        #pragma unroll
        for (int kk = 0; kk < 3; ++kk) {
            A[t4][kk] = *reinterpret_cast<const f16x8*>(ap + kk * 32);
            A[t4][3 + kk] = *reinterpret_cast<const f16x8*>(hp + kk * 32);
        }
    }

    // 2) cooperative wt staging: 96 cols x 24 chunks of 16B, coalesced
    #pragma unroll
    for (int c = 0; c < 9; ++c) {
        int i = tid + c * 256;
        int col = i / 24, seg = i % 24;
        *reinterpret_cast<u16x8*>(&sW[col][seg * 8]) =
            *reinterpret_cast<const u16x8*>(wt + (size_t)col * WPAD + seg * 8);
    }
    __syncthreads();

    // 3) MFMA loop, B from LDS, each fragment reused for 4 tiles
    f32x4 acc[4][6];
    #pragma unroll
    for (int t4 = 0; t4 < 4; ++t4)
        #pragma unroll
        for (int nn = 0; nn < 6; ++nn)
            acc[t4][nn] = (f32x4){0.f, 0.f, 0.f, 0.f};
    #pragma unroll
    for (int nn = 0; nn < 6; ++nn) {
        int col = nn * 16 + m16;
        #pragma unroll
        for (int kk = 0; kk < 6; ++kk) {
            f16x8 B = *reinterpret_cast<const f16x8*>(&sW[col][kk * 32 + hi * 8]);
            #pragma unroll
            for (int t4 = 0; t4 < 4; ++t4)
                acc[t4][nn] = __builtin_amdgcn_mfma_f32_16x16x32_f16(
                    A[t4][kk], B, acc[t4][nn], 0, 0, 0);
        }
    }

    // 4) epilogue: bias, fp16 stores, BN partials (all tiles) -> atomics
    #pragma unroll
    for (int nn = 0; nn < 6; ++nn) {
        int f = nn * 16 + m16;
        float bv = bias[f];
        float s = 0.f, q = 0.f;
        #pragma unroll
        for (int t4 = 0; t4 < 4; ++t4) {
            #pragma unroll
            for (int r = 0; r < 4; ++r) {
                int row = rbase + t4 * 64 + hi * 4 + r;
                float v = acc[t4][nn][r] + bv;
                if (row < n) {
                    hout[(size_t)row * D + f] = f2h(v);
                    s += v;
                    q += v * v;
                }
            }
        }
        s += __shfl_xor(s, 16); q += __shfl_xor(q, 16);
        s += __shfl_xor(s, 32); q += __shfl_xor(q, 32);
        if (lane < 16) {
            red[wave][f] = s;
            red[wave][96 + f] = q;
        }
    }
    __syncthreads();
    if (tid < 192) {
        float t = red[0][tid] + red[1][tid] + red[2][tid] + red[3][tid];
        atomicAdd(&stats[(blockIdx.x & (NREP - 1)) * 2 * D + tid], t);
    }
}

// fused final BN+ReLU + classifier (reads pre-BN h, writes logits directly)
__global__ void __launch_bounds__(256) apply_clf_kernel(
        const unsigned short* __restrict__ h,      // pre-BN fp16, layer 2
        const float* __restrict__ stats,
        const float* __restrict__ gamma,
        const float* __restrict__ beta,
        const float* __restrict__ W,
        const float* __restrict__ b,
        float* __restrict__ out, int n) {
    __shared__ float sW[D * NC];
    __shared__ float sB[NC];
    __shared__ float sC[2 * D];
    int tid = threadIdx.x;
    bn_fold(stats, gamma, beta, sC, tid);
    for (int i = tid; i < D * NC; i += blockDim.x) sW[i] = W[i];
    if (tid < NC) sB[tid] = b[tid];
    __syncthreads();
    int node = blockIdx.x * blockDim.x + tid;
    if (node >= n) return;
    float acc[NC];
    #pragma unroll
    for (int c = 0; c < NC; ++c) acc[c] = sB[c];
    const uint4* row = (const uint4*)(h + (size_t)node * D);
    #pragma unroll
    for (int q4 = 0; q4 < D / 8; ++q4) {
        uint4 v = row[q4];
        unsigned int* pv = (unsigned int*)&v;
        #pragma unroll
        for (int j = 0; j < 4; ++j) {
            int k = q4 * 8 + j * 2;
            h2t a = __builtin_bit_cast(h2t, pv[j]);
            float x0 = fmaxf(fmaf((float)a.x, sC[k], sC[D + k]), 0.f);
            float x1 = fmaxf(fmaf((float)a.y, sC[k + 1], sC[D + k + 1]), 0.f);
            #pragma unroll
            for (int c = 0; c < NC; ++c)
                acc[c] += x0 * sW[k * NC + c] + x1 * sW[(k + 1) * NC + c];
        }
    }
    float* orow = out + (size_t)node * NC;
    #pragma unroll
    for (int c = 0; c < NC; ++c) orow[c] = acc[c];
}

extern "C" void kernel_launch(void* const* d_in, const int* in_sizes, int n_in,
                              void* d_out, int out_size, void* d_ws, size_t ws_size,
                              hipStream_t stream) {
    const float* x      = (const float*)d_in[0];
    const void*  eidx   = d_in[1];
    const float* w_ngh  = (const float*)d_in[2];
    const float* w_self = (const float*)d_in[3];
    const float* bias   = (const float*)d_in[4];
    const float* gamma  = (const float*)d_in[5];
    const float* beta   = (const float*)d_in[6];
    const float* clf_w  = (const float*)d_in[7];
    const float* clf_b  = (const float*)d_in[8];
    float* out = (float*)d_out;

    char* ws = (char*)d_ws;
    size_t o = 0;
    auto alloc = [&](size_t bytes) -> void* {
        void* r = ws + o;
        o += (bytes + 255) & ~(size_t)255;
        return r;
    };
    int*   flag    = (int*)alloc(4);
    int*   row_ptr = (int*)alloc((size_t)(NN + 1) * 4);
    float* inv_deg = (float*)alloc((size_t)NN * 4);
    int*   csr_src = (int*)alloc((size_t)NE * 4);
    float* stats   = (float*)alloc((size_t)NL * NREP * 2 * D * 4);
    int*   cnt     = (int*)alloc((size_t)NB * 4);
    unsigned short* wt   = (unsigned short*)alloc((size_t)NL * D * WPAD * 2);
    unsigned short* xb   = (unsigned short*)alloc((size_t)NN * D * 2);
    unsigned short* aggb = (unsigned short*)alloc((size_t)NN * D * 2);
    unsigned short* hpre = (unsigned short*)alloc((size_t)NN * D * 2);
    unsigned short* hpA  = (unsigned short*)alloc((size_t)NN * D * 2);
    unsigned short* hpB  = (unsigned short*)alloc((size_t)NN * D * 2);
    // binned bucket regions alias hpA (dead until layer-0 bn_apply writes it)
    unsigned int* binned = (unsigned int*)hpA;   // NB*CAP*4 = 4.8MB <= 9.6MB

    prep_kernel<<<CASTB + PREPWB + 1, 256, 0, stream>>>(
        x, xb, w_ngh, w_self, wt, (const int*)eidx, flag, cnt, stats);
    bin_kernel<<<(NE + EPB - 1) / EPB, 256, 0, stream>>>(eidx, flag, cnt, binned, NE);
    fill_bucket_kernel<<<NB, 1024, 0, stream>>>(binned, cnt, row_ptr, inv_deg, csr_src);

    const unsigned short* hin = xb;   // layer input (post-BN for l>0)
    unsigned short* hpost[2] = {hpA, hpB};
    for (int l = 0; l < NL; ++l) {
        agg_kernel<<<(NN * 64 + 255) / 256, 256, 0, stream>>>(
            hin, row_ptr, csr_src, inv_deg, aggb, NN);
        mfma_gemm_kernel<<<(NN + 255) / 256, 256, 0, stream>>>(
            aggb, hin, wt + (size_t)l * D * WPAD, bias + (size_t)l * D,
            hpre, stats + (size_t)l * NREP * 2 * D, NN);
        if (l < NL - 1) {
            bn_apply_kernel<<<(NN * D / 8 + 255) / 256, 256, 0, stream>>>(
                hpre, stats + (size_t)l * NREP * 2 * D,
                gamma + (size_t)l * D, beta + (size_t)l * D, hpost[l]);
            hin = hpost[l];
        }
    }
    apply_clf_kernel<<<(NN + 255) / 256, 256, 0, stream>>>(
        hpre, stats + (size_t)2 * NREP * 2 * D, gamma + (size_t)2 * D,
        beta + (size_t)2 * D, clf_w, clf_b, out, NN);
}

// Round 13
// 168.686 us; speedup vs baseline: 1.0782x; 1.0782x over previous
//
#include <hip/hip_runtime.h>

#define NN 50000
#define NE 800000
#define D 96
#define NL 3
#define NC 10
#define BN_EPS 1e-5f
#define INV_N (1.0f / (float)NN)
#define NB 196          // buckets of 256 dst nodes (dst >> 8)
#define CAP 6144        // max edges per bucket (mean 4082, +32 sigma)
#define EPB 2048        // edges per bin block
#define NREP 16         // stats replication factor (atomic contention)
#define WPAD 200        // padded wt row stride (shorts); 400B keeps 16B alignment
#define CASTB ((NN * D / 4 + 255) / 256)       // 4688
#define PREPWB ((NL * D * 192 + 255) / 256)    // 216

typedef _Float16 f16x8 __attribute__((ext_vector_type(8)));
typedef _Float16 h2t __attribute__((ext_vector_type(2)));
typedef unsigned short u16x8 __attribute__((ext_vector_type(8)));
typedef unsigned int u32x3 __attribute__((ext_vector_type(3)));
typedef float f32x4 __attribute__((ext_vector_type(4)));

// ----------------------------- fp16 helpers ---------------------------------
__device__ __forceinline__ unsigned short f2h(float x) {
    _Float16 h = (_Float16)x;
    return __builtin_bit_cast(unsigned short, h);
}
__device__ __forceinline__ unsigned int pkh2(float lo, float hi) {
    auto r = __builtin_amdgcn_cvt_pkrtz(lo, hi);   // __fp16 ext_vector(2)
    return __builtin_bit_cast(unsigned int, r);
}
__device__ __forceinline__ unsigned int pkadd(unsigned int a, unsigned int b) {
    h2t x = __builtin_bit_cast(h2t, a);
    h2t y = __builtin_bit_cast(h2t, b);
    h2t z = x + y;
    return __builtin_bit_cast(unsigned int, z);
}

// ---------------- edge index access (int32 vs int64 auto-detect) -------------
__device__ __forceinline__ int edge_at(const void* idx, int is64, long long pos) {
    if (is64) return (int)((const long long*)idx)[pos];
    return ((const int*)idx)[pos];
}

// fold NREP stat replicas -> LDS scale/shift (called by every block; L2-hot)
__device__ __forceinline__ void bn_fold(const float* __restrict__ stats,
                                        const float* __restrict__ gamma,
                                        const float* __restrict__ beta,
                                        float* sC, int t) {
    if (t < D) {
        float s = 0.f, q = 0.f;
        #pragma unroll
        for (int r = 0; r < NREP; ++r) {
            s += stats[r * 2 * D + t];
            q += stats[r * 2 * D + D + t];
        }
        float mu = s * INV_N;
        float va = q * INV_N - mu * mu;
        float sc = rsqrtf(va + BN_EPS) * gamma[t];
        sC[t] = sc;
        sC[D + t] = beta[t] - mu * sc;
    }
}

// merged front-end: cast x->fp16 | build padded W_T fp16 | detect + zero
__global__ void __launch_bounds__(256) prep_kernel(
        const float* __restrict__ x, unsigned short* __restrict__ xb,
        const float* __restrict__ wn, const float* __restrict__ ws,
        unsigned short* __restrict__ wt,
        const int* __restrict__ words, int* __restrict__ flag,
        int* __restrict__ cnt, float* __restrict__ stats) {
    int b = blockIdx.x;
    int t = threadIdx.x;
    if (b < CASTB) {
        int i = b * 256 + t;
        if (i < NN * D / 4) {
            float4 v = ((const float4*)x)[i];
            ushort4 o;
            o.x = f2h(v.x); o.y = f2h(v.y); o.z = f2h(v.z); o.w = f2h(v.w);
            ((ushort4*)xb)[i] = o;
        }
        return;
    }
    if (b < CASTB + PREPWB) {
        int i = (b - CASTB) * 256 + t;
        if (i < NL * D * 192) {
            int k = i % 192;
            int col = (i / 192) % D;
            int l = i / (192 * D);
            float v = (k < D) ? wn[(size_t)l * D * D + k * D + col]
                              : ws[(size_t)l * D * D + (k - D) * D + col];
            wt[((size_t)l * D + col) * WPAD + k] = f2h(v);
        }
        return;
    }
    // last block: detect + zeros
    __shared__ int any_nz;
    if (t == 0) any_nz = 0;
    __syncthreads();
    if (words[2 * t + 1] != 0) atomicOr(&any_nz, 1);
    __syncthreads();
    if (t == 0) *flag = any_nz ? 0 : 1;   // 1 => int64
    if (t < NB) cnt[t] = 0;
    for (int i = t; i < NL * NREP * 2 * D; i += 256) stats[i] = 0.f;
}

// bucket edges by dst>>8; write (src<<8)|(dst&255) into per-bucket regions
__global__ void __launch_bounds__(256) bin_kernel(
        const void* __restrict__ idx, const int* __restrict__ flag,
        int* __restrict__ cnt, unsigned int* __restrict__ binned, int E) {
    __shared__ int hist[256];
    __shared__ int gbase[256];
    __shared__ unsigned int pk[EPB];
    __shared__ unsigned char bkt[EPB];
    int t = threadIdx.x;
    int base = blockIdx.x * EPB;
    int is64 = *flag;
    hist[t] = 0;
    __syncthreads();
    #pragma unroll
    for (int j = 0; j < 8; ++j) {
        int i = t + j * 256;
        int e = base + i;
        if (e < E) {
            int s = edge_at(idx, is64, e);
            int d = edge_at(idx, is64, (long long)E + e);
            int b = d >> 8;
            bkt[i] = (unsigned char)b;
            pk[i] = ((unsigned int)s << 8) | (unsigned int)(d & 255);
            atomicAdd(&hist[b], 1);
        } else {
            bkt[i] = 0xFF;
        }
    }
    __syncthreads();
    int h = hist[t];
    int gb = 0;
    if (t < NB && h > 0) gb = atomicAdd(&cnt[t], h);
    gbase[t] = gb;
    hist[t] = 0;
    __syncthreads();
    #pragma unroll
    for (int j = 0; j < 8; ++j) {
        int i = t + j * 256;
        int b = bkt[i];
        if (b != 0xFF) {
            int loc = atomicAdd(&hist[b], 1);
            int pos = gbase[b] + loc;
            if (pos < CAP) binned[(size_t)b * CAP + pos] = pk[i];
        }
    }
}

// per bucket: in-block scan of bucket counts -> base; LDS degree count ->
// scan -> row_ptr/inv_deg; LDS-local CSR scatter; coalesced copy-out
__global__ void __launch_bounds__(256) fill_bucket_kernel(
        const unsigned int* __restrict__ binned, const int* __restrict__ cnt,
        int* __restrict__ row_ptr, float* __restrict__ inv_deg,
        int* __restrict__ csr_src) {
    __shared__ int sexcl[256];
    __shared__ int deg_l[256];
    __shared__ int wsum[4];
    __shared__ int lds_csr[CAP];
    int b = blockIdx.x;
    int t = threadIdx.x;
    int lane = t & 63, w = t >> 6;
    {
        int v = (t < NB) ? cnt[t] : 0;
        int x = v;
        #pragma unroll
        for (int off = 1; off < 64; off <<= 1) {
            int y = __shfl_up(x, off);
            if (lane >= off) x += y;
        }
        if (lane == 63) wsum[w] = x;
        __syncthreads();
        if (t == 0) {
            int r = 0;
            #pragma unroll
            for (int i = 0; i < 4; ++i) { int tt = wsum[i]; wsum[i] = r; r += tt; }
        }
        __syncthreads();
        sexcl[t] = x - v + wsum[w];
        __syncthreads();
    }
    int base = sexcl[b];
    int count = cnt[b]; if (count > CAP) count = CAP;
    int n0 = b << 8;
    deg_l[t] = 0;
    __syncthreads();
    const unsigned int* reg = binned + (size_t)b * CAP;
    for (int i = t; i < count; i += 256) atomicAdd(&deg_l[reg[i] & 255], 1);
    __syncthreads();
    int v = deg_l[t];
    int x = v;
    #pragma unroll
    for (int off = 1; off < 64; off <<= 1) {
        int y = __shfl_up(x, off);
        if (lane >= off) x += y;
    }
    if (lane == 63) wsum[w] = x;
    __syncthreads();
    if (t == 0) {
        int r = 0;
        #pragma unroll
        for (int i = 0; i < 4; ++i) { int tt = wsum[i]; wsum[i] = r; r += tt; }
    }
    __syncthreads();
    int excl = x - v + wsum[w];
    int node = n0 + t;
    if (node < NN) {
        row_ptr[node] = base + excl;
        inv_deg[node] = 1.0f / (float)(v > 0 ? v : 1);
    }
    if (b == 0 && t == 0) row_ptr[NN] = NE;
    deg_l[t] = excl;   // reuse as fill cursor
    __syncthreads();
    for (int i = t; i < count; i += 256) {
        unsigned int pkv = reg[i];
        int loc = atomicAdd(&deg_l[pkv & 255], 1);
        lds_csr[loc] = (int)(pkv >> 8);
    }
    __syncthreads();
    for (int i = t; i < count; i += 256) csr_src[base + i] = lds_csr[i];
}

// materialize post-BN+ReLU fp16 h; BN coefs folded in-block from replicas
__global__ void __launch_bounds__(256) bn_apply_kernel(
        const unsigned short* __restrict__ hpre,
        const float* __restrict__ stats,
        const float* __restrict__ gamma,
        const float* __restrict__ beta,
        unsigned short* __restrict__ hpost) {
    __shared__ float sC[2 * D];
    int t = threadIdx.x;
    bn_fold(stats, gamma, beta, sC, t);
    __syncthreads();
    int i = blockIdx.x * 256 + t;
    if (i >= NN * D / 8) return;
    uint4 v = ((const uint4*)hpre)[i];
    int f0 = (i * 8) % D;
    unsigned int* pv = (unsigned int*)&v;
    uint4 o;
    unsigned int* po = (unsigned int*)&o;
    #pragma unroll
    for (int j = 0; j < 4; ++j) {
        int f = f0 + 2 * j;
        h2t a = __builtin_bit_cast(h2t, pv[j]);
        float x0 = fmaxf(fmaf((float)a.x, sC[f], sC[D + f]), 0.f);
        float x1 = fmaxf(fmaf((float)a.y, sC[f + 1], sC[D + f + 1]), 0.f);
        po[j] = pkh2(x0, x1);
    }
    ((uint4*)hpost)[i] = o;
}

// one wave per dst node: 4 groups x 16 lanes; each group keeps 4 edges in
// flight (16 loads/wave outstanding). Lane owns 12 bytes (6 fp16).
__global__ void agg_kernel(const unsigned short* __restrict__ hb,
                           const int* __restrict__ row_ptr,
                           const int* __restrict__ csr_src,
                           const float* __restrict__ inv_deg,
                           unsigned short* __restrict__ aggb, int n) {
    int gid = blockIdx.x * blockDim.x + threadIdx.x;
    int node = gid >> 6;
    int lane = gid & 63;
    if (node >= n) return;
    int g = lane >> 4;          // edge-slot group 0..3
    unsigned int p12 = (lane & 15) * 12u;
    int beg = row_ptr[node], end = row_ptr[node + 1];
    const char* hbase = (const char*)hb;

    u32x3 a0 = {0,0,0}, a1 = {0,0,0}, a2 = {0,0,0}, a3 = {0,0,0};
    int i0 = (beg + g      < end) ? csr_src[beg + g]      : -1;
    int i1 = (beg + 4 + g  < end) ? csr_src[beg + 4 + g]  : -1;
    int i2 = (beg + 8 + g  < end) ? csr_src[beg + 8 + g]  : -1;
    int i3 = (beg + 12 + g < end) ? csr_src[beg + 12 + g] : -1;
    int e = beg;
    while (e < end) {
        u32x3 u0 = {0,0,0}, u1 = {0,0,0}, u2 = {0,0,0}, u3 = {0,0,0};
        if (i0 >= 0) u0 = *(const u32x3*)(hbase + (unsigned)i0 * 192u + p12);
        if (i1 >= 0) u1 = *(const u32x3*)(hbase + (unsigned)i1 * 192u + p12);
        if (i2 >= 0) u2 = *(const u32x3*)(hbase + (unsigned)i2 * 192u + p12);
        if (i3 >= 0) u3 = *(const u32x3*)(hbase + (unsigned)i3 * 192u + p12);
        int en = e + 16;
        i0 = (en + g      < end) ? csr_src[en + g]      : -1;
        i1 = (en + 4 + g  < end) ? csr_src[en + 4 + g]  : -1;
        i2 = (en + 8 + g  < end) ? csr_src[en + 8 + g]  : -1;
        i3 = (en + 12 + g < end) ? csr_src[en + 12 + g] : -1;
        #pragma unroll
        for (int r = 0; r < 3; ++r) {
            a0[r] = pkadd(a0[r], u0[r]);
            a1[r] = pkadd(a1[r], u1[r]);
            a2[r] = pkadd(a2[r], u2[r]);
            a3[r] = pkadd(a3[r], u3[r]);
        }
        e = en;
    }
    // combine 4 chains + cross-group reduce (lanes L, L+16, L+32, L+48)
    unsigned int acc[3];
    #pragma unroll
    for (int r = 0; r < 3; ++r) {
        unsigned int a = pkadd(pkadd(a0[r], a1[r]), pkadd(a2[r], a3[r]));
        a = pkadd(a, (unsigned int)__shfl_xor((int)a, 16));
        a = pkadd(a, (unsigned int)__shfl_xor((int)a, 32));
        acc[r] = a;
    }
    if (lane < 16) {
        float idg = inv_deg[node];
        u32x3 o;
        #pragma unroll
        for (int r = 0; r < 3; ++r) {
            h2t av = __builtin_bit_cast(h2t, acc[r]);
            o[r] = pkh2((float)av.x * idg, (float)av.y * idg);
        }
        *(u32x3*)((char*)aggb + (unsigned)node * 192u + p12) = o;
    }
}

// MFMA fp16 GEMM + fused BN stats. 2 row-tiles (128 nodes) per block:
// wt staged once, B fragments reused for both tiles.
__global__ void __launch_bounds__(256) mfma_gemm_kernel(
        const unsigned short* __restrict__ aggb,
        const unsigned short* __restrict__ hb,     // post-BN (or xb for l=0)
        const unsigned short* __restrict__ wt,     // [96][WPAD] padded fp16
        const float* __restrict__ bias,
        unsigned short* __restrict__ hout,         // pre-BN fp16
        float* __restrict__ stats,                 // NREP replicas
        int n) {
    __shared__ float red[4][192];
    __shared__ unsigned short sW[D][WPAD];   // 38.4 KB
    int tid = threadIdx.x;
    int wave = tid >> 6;
    int lane = tid & 63;
    int m16 = lane & 15;
    int hi = lane >> 4;
    int rb0 = blockIdx.x * 128 + wave * 16;
    int rb1 = rb0 + 64;

    // 1) A-fragment global loads for both tiles (24 independent b128s)
    int ar0 = rb0 + m16; int ar0c = ar0 < n ? ar0 : n - 1;
    int ar1 = rb1 + m16; int ar1c = ar1 < n ? ar1 : n - 1;
    const unsigned short* ap0 = aggb + (size_t)ar0c * D + hi * 8;
    const unsigned short* hp0 = hb + (size_t)ar0c * D + hi * 8;
    const unsigned short* ap1 = aggb + (size_t)ar1c * D + hi * 8;
    const unsigned short* hp1 = hb + (size_t)ar1c * D + hi * 8;
    f16x8 A0[6], A1[6];
    #pragma unroll
    for (int kk = 0; kk < 3; ++kk) {
        A0[kk] = *reinterpret_cast<const f16x8*>(ap0 + kk * 32);
        A0[3 + kk] = *reinterpret_cast<const f16x8*>(hp0 + kk * 32);
        A1[kk] = *reinterpret_cast<const f16x8*>(ap1 + kk * 32);
        A1[3 + kk] = *reinterpret_cast<const f16x8*>(hp1 + kk * 32);
    }

    // 2) cooperative wt staging: 96 cols x 24 chunks of 16B, coalesced
    #pragma unroll
    for (int c = 0; c < 9; ++c) {
        int i = tid + c * 256;
        int col = i / 24, seg = i % 24;
        *reinterpret_cast<u16x8*>(&sW[col][seg * 8]) =
            *reinterpret_cast<const u16x8*>(wt + (size_t)col * WPAD + seg * 8);
    }
    __syncthreads();

    // 3) MFMA loop, B from LDS, reused for both tiles
    f32x4 acc0[6], acc1[6];
    #pragma unroll
    for (int nn = 0; nn < 6; ++nn) {
        acc0[nn] = (f32x4){0.f, 0.f, 0.f, 0.f};
        acc1[nn] = (f32x4){0.f, 0.f, 0.f, 0.f};
    }
    #pragma unroll
    for (int nn = 0; nn < 6; ++nn) {
        int col = nn * 16 + m16;
        #pragma unroll
        for (int kk = 0; kk < 6; ++kk) {
            f16x8 B = *reinterpret_cast<const f16x8*>(&sW[col][kk * 32 + hi * 8]);
            acc0[nn] = __builtin_amdgcn_mfma_f32_16x16x32_f16(A0[kk], B, acc0[nn], 0, 0, 0);
            acc1[nn] = __builtin_amdgcn_mfma_f32_16x16x32_f16(A1[kk], B, acc1[nn], 0, 0, 0);
        }
    }

    // 4) epilogue: bias, fp16 stores, BN partials (both tiles) -> atomics
    #pragma unroll
    for (int nn = 0; nn < 6; ++nn) {
        int f = nn * 16 + m16;
        float bv = bias[f];
        float s = 0.f, q = 0.f;
        #pragma unroll
        for (int r = 0; r < 4; ++r) {
            int row0 = rb0 + hi * 4 + r;
            float v0 = acc0[nn][r] + bv;
            if (row0 < n) {
                hout[(size_t)row0 * D + f] = f2h(v0);
                s += v0;
                q += v0 * v0;
            }
            int row1 = rb1 + hi * 4 + r;
            float v1 = acc1[nn][r] + bv;
            if (row1 < n) {
                hout[(size_t)row1 * D + f] = f2h(v1);
                s += v1;
                q += v1 * v1;
            }
        }
        s += __shfl_xor(s, 16); q += __shfl_xor(q, 16);
        s += __shfl_xor(s, 32); q += __shfl_xor(q, 32);
        if (lane < 16) {
            red[wave][f] = s;
            red[wave][96 + f] = q;
        }
    }
    __syncthreads();
    if (tid < 192) {
        float t = red[0][tid] + red[1][tid] + red[2][tid] + red[3][tid];
        atomicAdd(&stats[(blockIdx.x & (NREP - 1)) * 2 * D + tid], t);
    }
}

// fused final BN+ReLU + classifier (reads pre-BN h, writes logits directly)
__global__ void __launch_bounds__(256) apply_clf_kernel(
        const unsigned short* __restrict__ h,      // pre-BN fp16, layer 2
        const float* __restrict__ stats,
        const float* __restrict__ gamma,
        const float* __restrict__ beta,
        const float* __restrict__ W,
        const float* __restrict__ b,
        float* __restrict__ out, int n) {
    __shared__ float sW[D * NC];
    __shared__ float sB[NC];
    __shared__ float sC[2 * D];
    int tid = threadIdx.x;
    bn_fold(stats, gamma, beta, sC, tid);
    for (int i = tid; i < D * NC; i += blockDim.x) sW[i] = W[i];
    if (tid < NC) sB[tid] = b[tid];
    __syncthreads();
    int node = blockIdx.x * blockDim.x + tid;
    if (node >= n) return;
    float acc[NC];
    #pragma unroll
    for (int c = 0; c < NC; ++c) acc[c] = sB[c];
    const uint4* row = (const uint4*)(h + (size_t)node * D);
    #pragma unroll
    for (int q4 = 0; q4 < D / 8; ++q4) {
        uint4 v = row[q4];
        unsigned int* pv = (unsigned int*)&v;
        #pragma unroll
        for (int j = 0; j < 4; ++j) {
            int k = q4 * 8 + j * 2;
            h2t a = __builtin_bit_cast(h2t, pv[j]);
            float x0 = fmaxf(fmaf((float)a.x, sC[k], sC[D + k]), 0.f);
            float x1 = fmaxf(fmaf((float)a.y, sC[k + 1], sC[D + k + 1]), 0.f);
            #pragma unroll
            for (int c = 0; c < NC; ++c)
                acc[c] += x0 * sW[k * NC + c] + x1 * sW[(k + 1) * NC + c];
        }
    }
    float* orow = out + (size_t)node * NC;
    #pragma unroll
    for (int c = 0; c < NC; ++c) orow[c] = acc[c];
}

extern "C" void kernel_launch(void* const* d_in, const int* in_sizes, int n_in,
                              void* d_out, int out_size, void* d_ws, size_t ws_size,
                              hipStream_t stream) {
    const float* x      = (const float*)d_in[0];
    const void*  eidx   = d_in[1];
    const float* w_ngh  = (const float*)d_in[2];
    const float* w_self = (const float*)d_in[3];
    const float* bias   = (const float*)d_in[4];
    const float* gamma  = (const float*)d_in[5];
    const float* beta   = (const float*)d_in[6];
    const float* clf_w  = (const float*)d_in[7];
    const float* clf_b  = (const float*)d_in[8];
    float* out = (float*)d_out;

    char* ws = (char*)d_ws;
    size_t o = 0;
    auto alloc = [&](size_t bytes) -> void* {
        void* r = ws + o;
        o += (bytes + 255) & ~(size_t)255;
        return r;
    };
    int*   flag    = (int*)alloc(4);
    int*   row_ptr = (int*)alloc((size_t)(NN + 1) * 4);
    float* inv_deg = (float*)alloc((size_t)NN * 4);
    int*   csr_src = (int*)alloc((size_t)NE * 4);
    float* stats   = (float*)alloc((size_t)NL * NREP * 2 * D * 4);
    int*   cnt     = (int*)alloc((size_t)NB * 4);
    unsigned short* wt   = (unsigned short*)alloc((size_t)NL * D * WPAD * 2);
    unsigned short* xb   = (unsigned short*)alloc((size_t)NN * D * 2);
    unsigned short* aggb = (unsigned short*)alloc((size_t)NN * D * 2);
    unsigned short* hpre = (unsigned short*)alloc((size_t)NN * D * 2);
    unsigned short* hpA  = (unsigned short*)alloc((size_t)NN * D * 2);
    unsigned short* hpB  = (unsigned short*)alloc((size_t)NN * D * 2);
    // binned bucket regions alias hpA (dead until layer-0 bn_apply writes it)
    unsigned int* binned = (unsigned int*)hpA;   // NB*CAP*4 = 4.8MB <= 9.6MB

    prep_kernel<<<CASTB + PREPWB + 1, 256, 0, stream>>>(
        x, xb, w_ngh, w_self, wt, (const int*)eidx, flag, cnt, stats);
    bin_kernel<<<(NE + EPB - 1) / EPB, 256, 0, stream>>>(eidx, flag, cnt, binned, NE);
    fill_bucket_kernel<<<NB, 256, 0, stream>>>(binned, cnt, row_ptr, inv_deg, csr_src);

    const unsigned short* hin = xb;   // layer input (post-BN for l>0)
    unsigned short* hpost[2] = {hpA, hpB};
    for (int l = 0; l < NL; ++l) {
        agg_kernel<<<(NN * 64 + 255) / 256, 256, 0, stream>>>(
            hin, row_ptr, csr_src, inv_deg, aggb, NN);
        mfma_gemm_kernel<<<(NN + 127) / 128, 256, 0, stream>>>(
            aggb, hin, wt + (size_t)l * D * WPAD, bias + (size_t)l * D,
            hpre, stats + (size_t)l * NREP * 2 * D, NN);
        if (l < NL - 1) {
            bn_apply_kernel<<<(NN * D / 8 + 255) / 256, 256, 0, stream>>>(
                hpre, stats + (size_t)l * NREP * 2 * D,
                gamma + (size_t)l * D, beta + (size_t)l * D, hpost[l]);
            hin = hpost[l];
        }
    }
    apply_clf_kernel<<<(NN + 255) / 256, 256, 0, stream>>>(
        hpre, stats + (size_t)2 * NREP * 2 * D, gamma + (size_t)2 * D,
        beta + (size_t)2 * D, clf_w, clf_b, out, NN);
}